// Round 13
// baseline (1429.917 us; speedup 1.0000x reference)
//
#include <hip/hip_runtime.h>

typedef __bf16 bf16x8 __attribute__((ext_vector_type(8)));
typedef float  f32x4  __attribute__((ext_vector_type(4)));

#define KDIM 2048
#define NDIM 8192
#define MTOT 32768
#define BM 256
#define BN 256
#define BK 64
#define NT 32            // K-tiles
#define NMT 131          // grouped 256-row m-tiles
#define NWG (NMT * 32)
#define ABUF (BM * BK)   // one A buffer, elements
#define BBUF (BN * BK)

__device__ __forceinline__ void gload_lds16(const void* g, void* l) {
    __builtin_amdgcn_global_load_lds(
        (const __attribute__((address_space(1))) void*)g,
        (__attribute__((address_space(3))) void*)l, 16, 0, 0);
}

// ---------------- fp32 -> bf16 pre-pass ----------------
__global__ __launch_bounds__(256) void convert_f32_bf16(
    const float* __restrict__ src, __bf16* __restrict__ dst, int n8)
{
    const int stride = gridDim.x * blockDim.x;
    for (int i = blockIdx.x * blockDim.x + threadIdx.x; i < n8; i += stride) {
        const f32x4* p = (const f32x4*)(src + (size_t)i * 8);
        f32x4 a = p[0], b = p[1];
        bf16x8 h;
        #pragma unroll
        for (int j = 0; j < 4; ++j) { h[j] = (__bf16)a[j]; h[4 + j] = (__bf16)b[j]; }
        *(bf16x8*)(dst + (size_t)i * 8) = h;
    }
}

// ------------- 256x256 grouped GEMM, 3A+2B ring, post-barrier reads -------------
// R13: R10's 16x16 MFMA + exact zero-conflict read addressing, but ALL
// fragment reads move AFTER the barrier so the LDS drain overlaps the MFMA
// cluster (R10 measured phase = 1242 MFMA + 1152 LDS, additive).
// Safety: 3 A-buffers — A-stages target (a+2)%3, never a buffer being read
// (hazard removed by barriers, not latency). B keeps 2 buffers; B-stages
// land into a buffer whose reads drained into regs a full phase earlier.
// Ring (4 phases/iter, 4 gloads/wave/phase, vmcnt(8) at P1/P3):
//   P0: rdB(0), rdA(a0,h0), stageA->(a0+2)%3, MFMA, bar
//   P1: rdA(a0,h1), stageB->Bs[0], MFMA, vmcnt(8), bar
//   P2: rdB(1), rdA(a1,h0), stageA->a0, MFMA, bar
//   P3: rdA(a1,h1), stageB->Bs[1], MFMA, vmcnt(8), bar
// Every read: target staged >=2 phases back, drained by a vmcnt(8) BEFORE a
// barrier the reader crossed (collective). LDS = 96K + 64K = 160 KiB (HW max).
__global__ void __launch_bounds__(512, 2) moe_gemm_3a(
    const __bf16* __restrict__ A,   // [32768][2048] bf16
    const __bf16* __restrict__ W,   // [8][8192][2048] bf16
    float* __restrict__ C)          // [32768][8192] fp32
{
    __shared__ __bf16 AsF[3 * ABUF];   // 96 KiB
    __shared__ __bf16 BsF[2 * BBUF];   // 64 KiB

    const int tstart[9] = {0, 12, 32, 48, 56, 80, 96, 115, 131};
    const int offs[9]   = {0, 3000, 8000, 12096, 14144, 20144, 24144, 28768, 32768};

    const int bid = blockIdx.x;
    const int mt = bid >> 5;          // natural order, nt fastest (L3-friendly)
    const int nt = bid & 31;

    int e = 0;
    #pragma unroll
    for (int i = 1; i < 8; ++i) e += (mt >= tstart[i]) ? 1 : 0;
    const int row0 = offs[e] + (mt - tstart[e]) * BM;
    int rows = offs[e + 1] - row0;
    if (rows > BM) rows = BM;
    const int col0 = nt * BN;

    const int tid  = threadIdx.x;
    const int lane = tid & 63;
    const int w    = tid >> 6;
    const int wm   = w >> 2;          // 0..1
    const int wn   = w & 3;           // 0..3

    // ---- staging geometry (pre-swizzled global source; linear LDS dest) ----
    const int lrow = lane >> 3;                       // 0..7
    const int csrc = ((lane & 7) ^ lrow) * 8;         // swizzled source col (elems)

    const __bf16 *aX[2], *aY[2], *b0[2], *b1[2];
    int ldsAX[2], ldsAY[2], ldsB0[2], ldsB1[2];
    #pragma unroll
    for (int c = 0; c < 2; ++c) {
        const int q  = w * 2 + c;                     // 0..15
        const int tX = q * 8 + (q & 8) * 8;           // hX rows {0-63,128-191}
        const int tY = tX + 64;                       // hY rows {64-127,192-255}
        int rX = tX + lrow; rX = (rX < rows) ? rX : 0;   // clamp: never stored
        int rY = tY + lrow; rY = (rY < rows) ? rY : 0;
        aX[c] = A + (size_t)(row0 + rX) * KDIM + csrc;
        aY[c] = A + (size_t)(row0 + rY) * KDIM + csrc;
        b0[c] = W + (size_t)(e * NDIM + col0 + q * 8 + lrow) * KDIM + csrc;
        b1[c] = W + (size_t)(e * NDIM + col0 + 128 + q * 8 + lrow) * KDIM + csrc;
        ldsAX[c] = tX * BK;
        ldsAY[c] = tY * BK;
        ldsB0[c] = (q * 8) * BK;
        ldsB1[c] = (128 + q * 8) * BK;
    }

// full A-tile stage (AX+AY = 4 gloads) into buffer ab at k-offset o
#define STAGE_A(ab, o) { \
    gload_lds16(aX[0] + (o), &AsF[(ab) * ABUF + ldsAX[0]]); \
    gload_lds16(aX[1] + (o), &AsF[(ab) * ABUF + ldsAX[1]]); \
    gload_lds16(aY[0] + (o), &AsF[(ab) * ABUF + ldsAY[0]]); \
    gload_lds16(aY[1] + (o), &AsF[(ab) * ABUF + ldsAY[1]]); }
// full B-tile stage (B0+B1 = 4 gloads) into buffer bb at k-offset o
#define STAGE_B(bb, o) { \
    gload_lds16(b0[0] + (o), &BsF[(bb) * BBUF + ldsB0[0]]); \
    gload_lds16(b0[1] + (o), &BsF[(bb) * BBUF + ldsB0[1]]); \
    gload_lds16(b1[0] + (o), &BsF[(bb) * BBUF + ldsB1[0]]); \
    gload_lds16(b1[1] + (o), &BsF[(bb) * BBUF + ldsB1[1]]); }

    // ---- compute geometry (R10's exact zero-conflict read addressing) ----
    const int frow = lane & 15;
    const int g8   = (lane >> 4) * 8;
    const int swc  = (frow & 7) << 3;
    const int ck0  = g8 ^ swc;
    const int ck1  = (32 + g8) ^ swc;
    const int arow = wm * 128 + frow;
    const int brow = wn * 64 + frow;

    f32x4 acc[8][4];
    #pragma unroll
    for (int m = 0; m < 8; ++m)
        #pragma unroll
        for (int n = 0; n < 4; ++n)
            acc[m][n] = (f32x4){0.f, 0.f, 0.f, 0.f};

    bf16x8 bk0[4], bk1[4];
    bf16x8 av0[4], av1[4];

#define RD_B(bb) { _Pragma("unroll") for (int n = 0; n < 4; ++n) { \
        bk0[n] = *(const bf16x8*)&BsF[(bb) * BBUF + (brow + n * 16) * BK + ck0]; \
        bk1[n] = *(const bf16x8*)&BsF[(bb) * BBUF + (brow + n * 16) * BK + ck1]; } }

#define RD_A(ab, h) { _Pragma("unroll") for (int mm = 0; mm < 4; ++mm) { \
        av0[mm] = *(const bf16x8*)&AsF[(ab) * ABUF + (arow + (4 * (h) + mm) * 16) * BK + ck0]; \
        av1[mm] = *(const bf16x8*)&AsF[(ab) * ABUF + (arow + (4 * (h) + mm) * 16) * BK + ck1]; } }

#define MFMA_CL(h) { \
    __builtin_amdgcn_s_setprio(1); \
    _Pragma("unroll") for (int mm = 0; mm < 4; ++mm) \
        _Pragma("unroll") for (int n = 0; n < 4; ++n) \
            acc[4 * (h) + mm][n] = __builtin_amdgcn_mfma_f32_16x16x32_bf16( \
                av0[mm], bk0[n], acc[4 * (h) + mm][n], 0, 0, 0); \
    _Pragma("unroll") for (int mm = 0; mm < 4; ++mm) \
        _Pragma("unroll") for (int n = 0; n < 4; ++n) \
            acc[4 * (h) + mm][n] = __builtin_amdgcn_mfma_f32_16x16x32_bf16( \
                av1[mm], bk1[n], acc[4 * (h) + mm][n], 0, 0, 0); \
    __builtin_amdgcn_s_setprio(0); }

#define FENCE asm volatile("" ::: "memory")

    // ---- prologue: tile0 -> Abuf0/Bs0, tile1 -> Abuf1/Bs1 (16 gloads);
    // vmcnt(8) drains tile0's 8; barrier -> collective ----
    STAGE_A(0, 0); STAGE_B(0, 0);
    STAGE_A(1, BK); STAGE_B(1, BK);
    asm volatile("s_waitcnt vmcnt(8)" ::: "memory");
    __builtin_amdgcn_s_barrier();

    // ---- main loop: 16 iterations x 2 K-tiles, A-buf rotates mod 3 ----
    int a0 = 0;
    #pragma unroll 1
    for (int i = 0; i < 16; ++i) {
        int a1 = a0 + 1; if (a1 >= 3) a1 -= 3;
        int a2 = a0 + 2; if (a2 >= 3) a2 -= 3;
        int t2 = 2 * i + 2; if (t2 > NT - 1) t2 = NT - 1;   // clamped restage:
        int t3 = 2 * i + 3; if (t3 > NT - 1) t3 = NT - 1;   // same bytes, benign
        const int t2o = t2 * BK;
        const int t3o = t3 * BK;

        // P0: read buf a0 h0 + B0; stage A(t2)->a2 (not read this pair)
        FENCE;
        RD_B(0);
        RD_A(a0, 0);
        STAGE_A(a2, t2o);
        MFMA_CL(0);
        __builtin_amdgcn_s_barrier();

        // P1: read buf a0 h1; stage B(t2)->Bs0 (its reads drained in P0)
        FENCE;
        RD_A(a0, 1);
        STAGE_B(0, t2o);
        MFMA_CL(1);
        asm volatile("s_waitcnt vmcnt(8)" ::: "memory");
        __builtin_amdgcn_s_barrier();

        // P2: read buf a1 h0 + B1; stage A(t3)->a0 (its reads done in P0/P1)
        FENCE;
        RD_B(1);
        RD_A(a1, 0);
        STAGE_A(a0, t3o);
        MFMA_CL(0);
        __builtin_amdgcn_s_barrier();

        // P3: read buf a1 h1; stage B(t3)->Bs1 (reads drained in P2)
        FENCE;
        RD_A(a1, 1);
        STAGE_B(1, t3o);
        MFMA_CL(1);
        asm volatile("s_waitcnt vmcnt(8)" ::: "memory");
        __builtin_amdgcn_s_barrier();

        a0 = a2;   // next iteration reads tiles 2i+2 (buf a2), 2i+3 (buf a0)
    }

    // ---- epilogue: C/D layout col=lane&15, row=(lane>>4)*4+reg ----
    const int crow = (lane >> 4) * 4;
    const int ccol = lane & 15;
    #pragma unroll
    for (int m = 0; m < 8; ++m) {
        #pragma unroll
        for (int j2 = 0; j2 < 4; ++j2) {
            const int r = wm * 128 + m * 16 + crow + j2;
            if (r < rows) {
                float* dst = C + (size_t)(row0 + r) * NDIM + col0 + wn * 64 + ccol;
                #pragma unroll
                for (int n = 0; n < 4; ++n)
                    dst[n * 16] = acc[m][n][j2];
            }
        }
    }
#undef STAGE_A
#undef STAGE_B
#undef RD_B
#undef RD_A
#undef MFMA_CL
#undef FENCE
}

// ---------------- fallback (fused f32->bf16 staging) if ws too small ----------------
__global__ __launch_bounds__(256) void moe_gemm_f32(
    const float* __restrict__ A, const float* __restrict__ W, float* __restrict__ C)
{
    __shared__ __bf16 Asb[128][64];
    __shared__ __bf16 Bsb[128][64];

    const int tstart[9] = {0, 24, 64, 96, 112, 159, 191, 228, 260};
    const int offs[9]   = {0, 3000, 8000, 12096, 14144, 20144, 24144, 28768, 32768};

    const int mt = blockIdx.y;
    int e = 0;
    #pragma unroll
    for (int i = 1; i < 8; ++i) e += (mt >= tstart[i]) ? 1 : 0;
    const int row0 = offs[e] + (mt - tstart[e]) * 128;
    int rows = offs[e + 1] - row0;
    if (rows > 128) rows = 128;
    const int col0 = blockIdx.x * 128;

    const float* __restrict__ Abase = A + (size_t)row0 * KDIM;
    const float* __restrict__ Wbase = W + ((size_t)e * NDIM + (size_t)col0) * KDIM;

    const int tid  = threadIdx.x;
    const int lane = tid & 63;
    const int wid  = tid >> 6;
    const int wr   = (wid >> 1) * 64;
    const int wc   = (wid & 1) * 64;
    const int srow = tid >> 2;
    const int scol = (tid & 3) * 16;

    f32x4 acc[4][4];
    #pragma unroll
    for (int m = 0; m < 4; ++m)
        #pragma unroll
        for (int n = 0; n < 4; ++n)
            acc[m][n] = (f32x4){0.f, 0.f, 0.f, 0.f};
    const f32x4 fzero = (f32x4){0.f, 0.f, 0.f, 0.f};

    for (int k0 = 0; k0 < KDIM; k0 += 64) {
        __syncthreads();
        #pragma unroll
        for (int rr = 0; rr < 2; ++rr) {
            const int r = srow + rr * 64;
            {
                const bool valid = (r < rows);
                const float* pa = Abase + (size_t)r * KDIM + k0 + scol;
                f32x4 v[4];
                #pragma unroll
                for (int i = 0; i < 4; ++i) v[i] = valid ? *(const f32x4*)(pa + 4 * i) : fzero;
                bf16x8 h0, h1;
                #pragma unroll
                for (int i = 0; i < 8; ++i) {
                    h0[i] = (__bf16)v[i >> 2][i & 3];
                    h1[i] = (__bf16)v[2 + (i >> 2)][i & 3];
                }
                *((bf16x8*)&Asb[r][scol]) = h0;
                *((bf16x8*)&Asb[r][scol + 8]) = h1;
            }
            {
                const float* pb = Wbase + (size_t)r * KDIM + k0 + scol;
                f32x4 v[4];
                #pragma unroll
                for (int i = 0; i < 4; ++i) v[i] = *(const f32x4*)(pb + 4 * i);
                bf16x8 h0, h1;
                #pragma unroll
                for (int i = 0; i < 8; ++i) {
                    h0[i] = (__bf16)v[i >> 2][i & 3];
                    h1[i] = (__bf16)v[2 + (i >> 2)][i & 3];
                }
                *((bf16x8*)&Bsb[r][scol]) = h0;
                *((bf16x8*)&Bsb[r][scol + 8]) = h1;
            }
        }
        __syncthreads();
        #pragma unroll
        for (int ks = 0; ks < 2; ++ks) {
            const int kb = ks * 32 + (lane >> 4) * 8;
            bf16x8 af[4], bfr[4];
            #pragma unroll
            for (int m = 0; m < 4; ++m)
                af[m] = *((const bf16x8*)&Asb[wr + m * 16 + (lane & 15)][kb]);
            #pragma unroll
            for (int n = 0; n < 4; ++n)
                bfr[n] = *((const bf16x8*)&Bsb[wc + n * 16 + (lane & 15)][kb]);
            #pragma unroll
            for (int m = 0; m < 4; ++m)
                #pragma unroll
                for (int n = 0; n < 4; ++n)
                    acc[m][n] = __builtin_amdgcn_mfma_f32_16x16x32_bf16(
                        af[m], bfr[n], acc[m][n], 0, 0, 0);
        }
    }

    const int crow = (lane >> 4) * 4;
    const int ccol = lane & 15;
    #pragma unroll
    for (int m = 0; m < 4; ++m) {
        #pragma unroll
        for (int j = 0; j < 4; ++j) {
            const int r = wr + m * 16 + crow + j;
            if (r < rows) {
                float* dst = C + (size_t)(row0 + r) * NDIM + col0 + wc + ccol;
                #pragma unroll
                for (int n = 0; n < 4; ++n)
                    dst[n * 16] = acc[m][n][j];
            }
        }
    }
}

extern "C" void kernel_launch(void* const* d_in, const int* in_sizes, int n_in,
                              void* d_out, int out_size, void* d_ws, size_t ws_size,
                              hipStream_t stream) {
    const float* A = (const float*)d_in[0];
    const float* W = (const float*)d_in[1];
    float* C = (float*)d_out;

    const size_t nA = (size_t)MTOT * KDIM;
    const size_t nW = (size_t)8 * NDIM * KDIM;
    const size_t WS_NEED = (nA + nW) * 2;

    if (ws_size >= WS_NEED) {
        __bf16* Abf = (__bf16*)d_ws;
        __bf16* Wbf = (__bf16*)((char*)d_ws + nA * 2);
        hipLaunchKernelGGL(convert_f32_bf16, dim3(2048), dim3(256), 0, stream,
                           A, Abf, (int)(nA / 8));
        hipLaunchKernelGGL(convert_f32_bf16, dim3(2048), dim3(256), 0, stream,
                           W, Wbf, (int)(nW / 8));
        hipLaunchKernelGGL(moe_gemm_3a, dim3(NWG), dim3(512), 0, stream,
                           Abf, Wbf, C);
    } else {
        hipLaunchKernelGGL(moe_gemm_f32, dim3(NDIM / 128, 260), dim3(256), 0, stream,
                           A, W, C);
    }
}